// Round 8
// baseline (388.026 us; speedup 1.0000x reference)
//
#include <hip/hip_runtime.h>
#include <hip/hip_fp16.h>
#include <math.h>

// R7: radix CSR build. R12: fp16 gather table. R13: MFMA GEMM. R16/R17:
// 16-lanes/node aggregate + 32-deep ILP staging -> ~32us/pass (~6TB/s
// effective = random-gather fabric ceiling). 324.9us total.
// R18 (this round): build-phase restructure (build ~130-150us is now the
// dominant cost; every kernel <41.7us per R7 top-5 fill-pollution bound).
// (a) global deg[] accumulated in block_hist -> bucket_build drops its
//     1st grouped pass (6.4MB + 1.6M LDS atomics saved);
// (b) EPB 8192->6272 => 256 blocks = full CU coverage for hist/group;
// (c) logits fused into pool (kernel + gap + lb round-trip removed).

#define BKT_SHIFT 7
#define BKT_NODES 128
#define BKT_CAP 4096   // LDS staging cap; overflow -> direct-write fallback
#define EPB 6272       // edges per block: ceil(1.6M/6272)=256 blocks (<=256)

typedef _Float16 f16x8 __attribute__((ext_vector_type(8)));
typedef float f32x4 __attribute__((ext_vector_type(4)));

// ------- phase A: per-(bucket,block) histogram + global node degree -----
__global__ __launch_bounds__(1024) void block_hist_kernel(
    const int* __restrict__ dst, int* __restrict__ hist, int* __restrict__ deg,
    int E, int NBKT, int NBLK) {
  __shared__ int lh[1024];  // >= NBKT
  const int t = threadIdx.x;
  const int blk = blockIdx.x;
  for (int k = t; k < NBKT; k += 1024) lh[k] = 0;
  __syncthreads();
  const int e0 = blk * EPB;
  const int e1 = min(e0 + EPB, E);
  for (int e = e0 + t; e < e1; e += 1024) {
    int d = dst[e];
    atomicAdd(&lh[d >> BKT_SHIFT], 1);
    atomicAdd(&deg[d], 1);           // L2-resident int atomic (native)
  }
  __syncthreads();
  for (int k = t; k < NBKT; k += 1024) hist[k * NBLK + blk] = lh[k];
}

// ---------------- phase B1: per-bucket row scan (grid-parallel) ----------
__global__ __launch_bounds__(256) void row_scan_kernel(
    const int* __restrict__ hist, int* __restrict__ ebase, int* __restrict__ btot,
    int NBLK) {
  __shared__ int sh[256];
  const int k = blockIdx.x;
  const int t = threadIdx.x;
  int v = (t < NBLK) ? hist[(long)k * NBLK + t] : 0;
  sh[t] = v;
  __syncthreads();
  for (int s = 1; s < 256; s <<= 1) {
    int add = (t >= s) ? sh[t - s] : 0;
    __syncthreads();
    sh[t] += add;
    __syncthreads();
  }
  if (t < NBLK) ebase[(long)k * NBLK + t] = sh[t] - v;  // row-local exclusive
  if (t == 255) btot[k] = sh[255];
}

// ---------------- phase B2: scan bucket totals (single block, LDS-only) --
__global__ __launch_bounds__(1024) void bucket_scan_kernel(
    const int* __restrict__ btot, int* __restrict__ bbase, int E, int NBKT) {
  __shared__ int sh[1024];
  const int t = threadIdx.x;
  int v = (t < NBKT) ? btot[t] : 0;
  sh[t] = v;
  __syncthreads();
  for (int s = 1; s < 1024; s <<= 1) {
    int add = (t >= s) ? sh[t - s] : 0;
    __syncthreads();
    sh[t] += add;
    __syncthreads();
  }
  if (t < NBKT) bbase[t] = sh[t] - v;
  if (t == 0) bbase[NBKT] = E;
}

// ---------------- phase C: group edges by bucket (sequential runs) --------
__global__ __launch_bounds__(1024) void group_kernel(
    const int* __restrict__ src, const int* __restrict__ dst,
    const int* __restrict__ bbase, const int* __restrict__ ebase,
    unsigned int* __restrict__ grouped, int E, int NBKT, int NBLK) {
  __shared__ int lcur[1024];
  const int t = threadIdx.x;
  const int blk = blockIdx.x;
  for (int k = t; k < NBKT; k += 1024)
    lcur[k] = bbase[k] + ebase[(long)k * NBLK + blk];
  __syncthreads();
  const int e0 = blk * EPB;
  const int e1 = min(e0 + EPB, E);
  for (int e = e0 + t; e < e1; e += 1024) {
    int d = dst[e];
    int b = d >> BKT_SHIFT;
    int pos = atomicAdd(&lcur[b], 1);
    grouped[pos] = ((unsigned int)(d & (BKT_NODES - 1)) << 17) | (unsigned int)src[e];
  }
}

// ------- phase D (slim): scan deg -> ends/dis, scatter grouped -> csr ----
__global__ __launch_bounds__(256) void bucket_build_kernel(
    const unsigned int* __restrict__ grouped, const int* __restrict__ bbase,
    const int* __restrict__ deg, int* __restrict__ csr_src,
    int* __restrict__ ends, float* __restrict__ dis, int N) {
  __shared__ int lcnt[BKT_NODES];
  __shared__ int lsum[BKT_NODES];
  __shared__ int lcur[BKT_NODES];
  __shared__ int stage[BKT_CAP];
  const int b = blockIdx.x;
  const int t = threadIdx.x;
  const int node0 = b << BKT_SHIFT;
  const int nn = min(BKT_NODES, N - node0);
  const int base = bbase[b];
  const int m = bbase[b + 1] - base;

  if (t < BKT_NODES) {
    int cnt = (t < nn) ? deg[node0 + t] : 0;   // coalesced, replaces hist pass
    lcnt[t] = cnt;
    lsum[t] = cnt;
  }
  __syncthreads();
  for (int s = 1; s < BKT_NODES; s <<= 1) {
    int add = 0;
    if (t < BKT_NODES && t >= s) add = lsum[t - s];
    __syncthreads();
    if (t < BKT_NODES) lsum[t] += add;
    __syncthreads();
  }
  if (t < nn) {
    ends[node0 + t] = base + lsum[t];                      // global inclusive end
    dis[node0 + t] = 1.0f / sqrtf((float)(lcnt[t] + 1));   // +1 self loop
    lcur[t] = lsum[t] - lcnt[t];                           // local exclusive cursor
  }
  __syncthreads();
  if (m <= BKT_CAP) {
    for (int i = t; i < m; i += 256) {
      unsigned int v = grouped[base + i];
      int p = atomicAdd(&lcur[v >> 17], 1);
      stage[p] = (int)(v & 0x1FFFFu);
    }
    __syncthreads();
    for (int i = t; i < m; i += 256) csr_src[base + i] = stage[i];
  } else {  // statistically never; correctness fallback
    for (int i = t; i < m; i += 256) {
      unsigned int v = grouped[base + i];
      int p = atomicAdd(&lcur[v >> 17], 1);
      csr_src[base + p] = (int)(v & 0x1FFFFu);
    }
  }
}

// ------- MFMA GEMM: C[N,64] = fp16( (H[N,K] @ W[K,64]) * dis[row] ) -----
// 64 rows/block, 256 thr = 4 waves; wave w owns rows 16w..16w+15.
// Whole K staged: Hs[64][K] fp16, Ws[64][K] fp16 (= W^T), both XOR-swizzled.

template <int K, typename Tin>
__global__ __launch_bounds__(256) void gemm_mfma_kernel(
    const Tin* __restrict__ H, const float* __restrict__ W,
    const float* __restrict__ dis, __half* __restrict__ C, int N) {
  __shared__ __align__(16) __half Hs[64 * K];
  __shared__ __align__(16) __half Ws[64 * K];
  const int t = threadIdx.x;
  const int rowBase = blockIdx.x * 64;

  // ---- stage H (cast to fp16, swizzled) ----
  if constexpr (sizeof(Tin) == 4) {
    const int NF4 = 64 * K / 4;
#pragma unroll
    for (int i = 0; i < NF4 / 256; ++i) {
      int f = t + i * 256;
      int row = f / (K / 4);
      int c4 = f % (K / 4);
      int gr = rowBase + row;
      float4 v = make_float4(0.f, 0.f, 0.f, 0.f);
      if (gr < N) v = *reinterpret_cast<const float4*>(H + (long)gr * K + c4 * 4);
      union { uint2 u; __half2 h[2]; } pk;
      pk.h[0] = __floats2half2_rn(v.x, v.y);
      pk.h[1] = __floats2half2_rn(v.z, v.w);
      int byte = (row * K + c4 * 4) * 2;
      byte ^= (row & 7) << 4;
      *reinterpret_cast<uint2*>(reinterpret_cast<char*>(Hs) + byte) = pk.u;
    }
  } else {
    const int NC = 64 * K / 8;
#pragma unroll
    for (int i = 0; i < NC / 256; ++i) {
      int f = t + i * 256;
      int row = f / (K / 8);
      int c8 = f % (K / 8);
      int gr = rowBase + row;
      uint4 v = make_uint4(0u, 0u, 0u, 0u);
      if (gr < N) v = *reinterpret_cast<const uint4*>(H + (long)gr * K + c8 * 8);
      int byte = (row * K + c8 * 8) * 2;
      byte ^= (row & 7) << 4;
      *reinterpret_cast<uint4*>(reinterpret_cast<char*>(Hs) + byte) = v;
    }
  }

  // ---- stage W^T (transpose via half2 k-pairs, swizzled) ----
  {
    const int NU = (K / 2) * 16;  // (k-pair, col-quad) units
#pragma unroll
    for (int i = 0; i < NU / 256; ++i) {
      int u = t + i * 256;
      int kp = u >> 4;
      int cq = u & 15;
      const float4 w0 = *reinterpret_cast<const float4*>(W + (long)(2 * kp) * 64 + cq * 4);
      const float4 w1 = *reinterpret_cast<const float4*>(W + (long)(2 * kp + 1) * 64 + cq * 4);
#pragma unroll
      for (int j = 0; j < 4; ++j) {
        int c = cq * 4 + j;
        __half2 p = __floats2half2_rn((&w0.x)[j], (&w1.x)[j]);
        int byte = (c * K + 2 * kp) * 2;
        byte ^= (c & 7) << 4;
        *reinterpret_cast<__half2*>(reinterpret_cast<char*>(Ws) + byte) = p;
      }
    }
  }
  __syncthreads();

  // ---- MFMA: wave computes 16 rows x 64 cols ----
  const int w = t >> 6;
  const int l = t & 63;
  const int r = l & 15;
  const int g = l >> 4;
  const int rowL = 16 * w + r;
  f32x4 acc[4] = {{0.f, 0.f, 0.f, 0.f}, {0.f, 0.f, 0.f, 0.f},
                  {0.f, 0.f, 0.f, 0.f}, {0.f, 0.f, 0.f, 0.f}};
#pragma unroll
  for (int s = 0; s < K / 32; ++s) {
    int abyte = (rowL * K + s * 32 + g * 8) * 2;
    abyte ^= (rowL & 7) << 4;
    f16x8 afrag = *reinterpret_cast<const f16x8*>(reinterpret_cast<const char*>(Hs) + abyte);
#pragma unroll
    for (int n = 0; n < 4; ++n) {
      int col = n * 16 + r;
      int bbyte = (col * K + s * 32 + g * 8) * 2;
      bbyte ^= (col & 7) << 4;
      f16x8 bfrag = *reinterpret_cast<const f16x8*>(reinterpret_cast<const char*>(Ws) + bbyte);
      acc[n] = __builtin_amdgcn_mfma_f32_16x16x32_f16(afrag, bfrag, acc[n], 0, 0, 0);
    }
  }

  // ---- epilogue: scale by dis[row], round to fp16 ----
  const int outRow0 = rowBase + 16 * w + 4 * g;
#pragma unroll
  for (int j = 0; j < 4; ++j) {
    int row = outRow0 + j;
    if (row < N) {
      float dv = dis[row];
#pragma unroll
      for (int n = 0; n < 4; ++n) {
        C[(long)row * 64 + n * 16 + r] = __float2half(acc[n][j] * dv);
      }
    }
  }
}

// -------- aggregation: CSR, 16 lanes/node, 4 nodes/wave, deep ILP --------
// Lane (g,c) owns cols 4c..4c+3 of node d=wid*4+g. Chunks 0+1 (32 edges)
// fully staged: idx prefetched, 32 row-loads issued before ANY accumulate
// (pad lanes clamp to row d = L1-hot). Dynamic tail for degree>32 only.

__device__ __forceinline__ float4 h4_to_f4(uint2 u) {
  const __half2 lo = *reinterpret_cast<const __half2*>(&u.x);
  const __half2 hi = *reinterpret_cast<const __half2*>(&u.y);
  const float2 flo = __half22float2(lo);
  const float2 fhi = __half22float2(hi);
  return make_float4(flo.x, flo.y, fhi.x, fhi.y);
}

__global__ __launch_bounds__(256) void aggregate_kernel(
    const __half* __restrict__ Ts, const int* __restrict__ csr_src,
    const int* __restrict__ ends, const float* __restrict__ dis,
    const float* __restrict__ bias, __half* __restrict__ O, int N) {
  const int wid = (blockIdx.x * 256 + threadIdx.x) >> 6;
  const int l = threadIdx.x & 63;
  const int g = l >> 4;         // node within wave quad
  const int c = l & 15;         // uint2 column of the 128B row
  const int d0 = wid * 4 + g;
  const bool valid = d0 < N;
  const int d = valid ? d0 : (N - 1);   // safe row for pad lanes
  const int beg = valid ? ((d0 == 0) ? 0 : ends[d0 - 1]) : 0;
  const int m = valid ? (ends[d0] - beg) : 0;   // group-uniform per valid group
  const uint2* Tv = (const uint2*)Ts;

  // self loop (pre-scaled by dis[d])
  float4 a = h4_to_f4(Tv[(long)d * 16 + c]);

  // wave-uniform outer trip count so shfl stays convergent
  int mmax = m;
  mmax = max(mmax, __shfl_xor(mmax, 16, 64));
  mmax = max(mmax, __shfl_xor(mmax, 32, 64));

  const int gbase = l & 48;     // first lane of this group

  // ---- prefetch indices for chunks 0 and 1 ----
  int idx0 = (c < m) ? csr_src[beg + c] : 0;
  int idx1 = (16 + c < m) ? csr_src[beg + 16 + c] : 0;

  // ---- stage all 32 row loads before accumulating ----
  uint2 fr0[16], fr1[16];
  const bool has0 = (mmax > 0), has1 = (mmax > 16);
  if (has0) {
#pragma unroll
    for (int j = 0; j < 16; ++j) {
      int s = __shfl(idx0, gbase + j, 64);
      s = (j < m) ? s : d;              // pad -> own row (L1-hot)
      fr0[j] = Tv[(long)s * 16 + c];
    }
  }
  if (has1) {
#pragma unroll
    for (int j = 0; j < 16; ++j) {
      int s = __shfl(idx1, gbase + j, 64);
      s = (j + 16 < m) ? s : d;
      fr1[j] = Tv[(long)s * 16 + c];
    }
  }
  if (has0) {
#pragma unroll
    for (int j = 0; j < 16; ++j) {
      if (j < m) {
        float4 f = h4_to_f4(fr0[j]);
        a.x += f.x; a.y += f.y; a.z += f.z; a.w += f.w;
      }
    }
  }
  if (has1) {
#pragma unroll
    for (int j = 0; j < 16; ++j) {
      if (j + 16 < m) {
        float4 f = h4_to_f4(fr1[j]);
        a.x += f.x; a.y += f.y; a.z += f.z; a.w += f.w;
      }
    }
  }

  // ---- dynamic tail (degree > 32; Poisson(16) => rare) ----
  for (int base = 32; base < mmax; base += 16) {
    const int take = m - base;
    int idx = (base + c < m) ? csr_src[beg + base + c] : 0;
    uint2 fr[16];
#pragma unroll
    for (int j = 0; j < 16; ++j) {
      int s = __shfl(idx, gbase + j, 64);
      s = (j < take) ? s : d;
      fr[j] = Tv[(long)s * 16 + c];
    }
#pragma unroll
    for (int j = 0; j < 16; ++j) {
      if (j < take) {
        float4 f = h4_to_f4(fr[j]);
        a.x += f.x; a.y += f.y; a.z += f.z; a.w += f.w;
      }
    }
  }

  if (valid) {
    const float dd = dis[d0];
    const float4 b4 = ((const float4*)bias)[c];
    union { uint2 uu; __half2 h[2]; } pk;
    pk.h[0] = __floats2half2_rn(fmaxf(a.x * dd + b4.x, 0.f),
                                fmaxf(a.y * dd + b4.y, 0.f));
    pk.h[1] = __floats2half2_rn(fmaxf(a.z * dd + b4.z, 0.f),
                                fmaxf(a.w * dd + b4.w, 0.f));
    ((uint2*)O)[(long)d0 * 16 + c] = pk.uu;
  }
}

// ---------------- pooling (logits fused) ----------------

__global__ __launch_bounds__(256) void pool_kernel(
    const __half* __restrict__ h3, const float* __restrict__ clo,
    const float* __restrict__ Wc, const float* __restrict__ bc,
    const int* __restrict__ batch, const float* __restrict__ Wa1,
    const float* __restrict__ ba1, const float* __restrict__ Wa2,
    const float* __restrict__ ba2, float* __restrict__ out, int N) {
  __shared__ int sLo, sHi;
  __shared__ float red[256];
  __shared__ float Vs[4][64];
  __shared__ float sse[4];
  __shared__ float gv[64];
  __shared__ float am[16];
  const int g = blockIdx.x;
  const int t = threadIdx.x;
  if (t == 0) {
    int lo = 0, hi = N;
    while (lo < hi) { int mid = (lo + hi) >> 1; if (batch[mid] < g) lo = mid + 1; else hi = mid; }
    sLo = lo;
    lo = 0; hi = N;
    while (lo < hi) { int mid = (lo + hi) >> 1; if (batch[mid] < g + 1) lo = mid + 1; else hi = mid; }
    sHi = lo;
  }
  __syncthreads();
  const int lo = sLo, hi = sHi;

  // logits computed inline: lb(i) = dot(clo[i,0:8], Wc) + bc
  float wc[8];
#pragma unroll
  for (int k = 0; k < 8; ++k) wc[k] = Wc[k];
  const float bc0 = bc[0];

  float lm = -1e30f;
  for (int i = lo + t; i < hi; i += 256) {
    const float4 c0 = *reinterpret_cast<const float4*>(clo + (long)i * 8);
    const float4 c1 = *reinterpret_cast<const float4*>(clo + (long)i * 8 + 4);
    float s = bc0 + c0.x * wc[0] + c0.y * wc[1] + c0.z * wc[2] + c0.w * wc[3]
                  + c1.x * wc[4] + c1.y * wc[5] + c1.z * wc[6] + c1.w * wc[7];
    lm = fmaxf(lm, s);
  }
  red[t] = lm;
  __syncthreads();
  for (int s = 128; s > 0; s >>= 1) {
    if (t < s) red[t] = fmaxf(red[t], red[t + s]);
    __syncthreads();
  }
  const float m = red[0];

  const int f = t & 63, sub = t >> 6;
  float vacc = 0.f, seacc = 0.f;
  for (int i = lo + sub; i < hi; i += 4) {
    const float4 c0 = *reinterpret_cast<const float4*>(clo + (long)i * 8);
    const float4 c1 = *reinterpret_cast<const float4*>(clo + (long)i * 8 + 4);
    float s = bc0 + c0.x * wc[0] + c0.y * wc[1] + c0.z * wc[2] + c0.w * wc[3]
                  + c1.x * wc[4] + c1.y * wc[5] + c1.z * wc[6] + c1.w * wc[7];
    float e = expf(s - m);
    seacc += e;
    vacc += e * __half2float(h3[(long)i * 64 + f]);
  }
  Vs[sub][f] = vacc;
  if (f == 0) sse[sub] = seacc;
  __syncthreads();
  if (t < 64) {
    float se = sse[0] + sse[1] + sse[2] + sse[3];
    float v = Vs[0][f] + Vs[1][f] + Vs[2][f] + Vs[3][f];
    gv[f] = (se > 0.f) ? v / se : 0.f;
  }
  __syncthreads();
  if (t < 16) {
    float a = ba1[t];
#pragma unroll
    for (int k2 = 0; k2 < 64; ++k2) a += gv[k2] * Wa1[k2 * 16 + t];
    am[t] = a > 0.f ? a : 0.f;
  }
  __syncthreads();
  if (t == 0) {
    float o = ba2[0];
#pragma unroll
    for (int j = 0; j < 16; ++j) o += am[j] * Wa2[j];
    out[g] = o;
  }
}

// ---------------- launcher ----------------

extern "C" void kernel_launch(void* const* d_in, const int* in_sizes, int n_in,
                              void* d_out, int out_size, void* d_ws, size_t ws_size,
                              hipStream_t stream) {
  const float* x   = (const float*)d_in[0];
  const float* clo = (const float*)d_in[1];
  const float* W1  = (const float*)d_in[2];
  const float* b1  = (const float*)d_in[3];
  const float* W2  = (const float*)d_in[4];
  const float* b2  = (const float*)d_in[5];
  const float* W3  = (const float*)d_in[6];
  const float* b3  = (const float*)d_in[7];
  const float* Wc  = (const float*)d_in[8];
  const float* bc  = (const float*)d_in[9];
  const float* Wa1 = (const float*)d_in[10];
  const float* ba1 = (const float*)d_in[11];
  const float* Wa2 = (const float*)d_in[12];
  const float* ba2 = (const float*)d_in[13];
  const int* edge  = (const int*)d_in[14];
  const int* batch = (const int*)d_in[15];
  float* out = (float*)d_out;

  const int N = in_sizes[15];        // 100000
  const int E = in_sizes[14] / 2;    // 1600000
  const int G = out_size;            // 256
  const int NBKT = (N + BKT_NODES - 1) >> BKT_SHIFT;  // 782 (<=1024)
  const int NBLK = (E + EPB - 1) / EPB;               // 256 (<=256)

  const int* src = edge;
  const int* dst = edge + E;

  char* p = (char*)d_ws;
  auto alloc = [&](size_t bytes) -> char* {
    char* r = p;
    p += (bytes + 255) & ~(size_t)255;
    return r;
  };
  __half* tsbuf         = (__half*)alloc((size_t)N * 64 * sizeof(__half));
  __half* bufH          = (__half*)alloc((size_t)N * 64 * sizeof(__half));
  int*   csr_src        = (int*)  alloc((size_t)E * sizeof(int));
  unsigned int* grouped = (unsigned int*)alloc((size_t)E * sizeof(unsigned int));
  int*   hist           = (int*)  alloc((size_t)NBKT * NBLK * sizeof(int));
  int*   ebase          = (int*)  alloc((size_t)NBKT * NBLK * sizeof(int));
  int*   btot           = (int*)  alloc((size_t)NBKT * sizeof(int));
  int*   bbase          = (int*)  alloc((size_t)(NBKT + 1) * sizeof(int));
  int*   ends           = (int*)  alloc((size_t)N * sizeof(int));
  int*   deg            = (int*)  alloc((size_t)N * sizeof(int));
  float* dis            = (float*)alloc((size_t)N * sizeof(float));
  (void)ws_size; (void)n_in;

  hipMemsetAsync(deg, 0, (size_t)N * sizeof(int), stream);
  block_hist_kernel<<<NBLK, 1024, 0, stream>>>(dst, hist, deg, E, NBKT, NBLK);
  row_scan_kernel<<<NBKT, 256, 0, stream>>>(hist, ebase, btot, NBLK);
  bucket_scan_kernel<<<1, 1024, 0, stream>>>(btot, bbase, E, NBKT);
  group_kernel<<<NBLK, 1024, 0, stream>>>(src, dst, bbase, ebase, grouped, E, NBKT, NBLK);
  bucket_build_kernel<<<NBKT, 256, 0, stream>>>(grouped, bbase, deg, csr_src, ends, dis, N);

  const int gGemm = (N + 63) / 64;
  const int gAgg  = (N + 15) / 16;   // 16 nodes per 256-thread block

  gemm_mfma_kernel<128, float><<<gGemm, 256, 0, stream>>>(x, W1, dis, tsbuf, N);
  aggregate_kernel<<<gAgg, 256, 0, stream>>>(tsbuf, csr_src, ends, dis, b1, bufH, N);
  gemm_mfma_kernel<64, __half><<<gGemm, 256, 0, stream>>>(bufH, W2, dis, tsbuf, N);
  aggregate_kernel<<<gAgg, 256, 0, stream>>>(tsbuf, csr_src, ends, dis, b2, bufH, N);
  gemm_mfma_kernel<64, __half><<<gGemm, 256, 0, stream>>>(bufH, W3, dis, tsbuf, N);
  aggregate_kernel<<<gAgg, 256, 0, stream>>>(tsbuf, csr_src, ends, dis, b3, bufH, N);

  pool_kernel<<<G, 256, 0, stream>>>(bufH, clo, Wc, bc, batch, Wa1, ba1, Wa2, ba2, out, N);
}

// Round 9
// 326.144 us; speedup vs baseline: 1.1897x; 1.1897x over previous
//
#include <hip/hip_runtime.h>
#include <hip/hip_fp16.h>
#include <math.h>

// R7: radix CSR build. R12: fp16 gather table. R13: MFMA GEMM. R16/R17:
// 16-lanes/node aggregate + 32-deep ILP staging (~6TB/s effective =
// random-gather fabric ceiling) -> 324.9us.
// R18 FAILED (+63us): per-edge global atomicAdd(deg) in block_hist was
// latency-serialized (VALU 0.55%, WRITE 56MB). Lesson: random fine-grained
// atomics (LDS fp32 OR global int) are the losing primitive here; the
// contention-free radix structure exists to avoid them.
// R19 (this round): clean revert to R17 (two-pass bucket_build, EPB 8192,
// no deg/memset), keeping ONLY the logits->pool fusion (correctness
// verified by R18's absmax 9.5e-7; one fewer launch + no lb round-trip).

#define BKT_SHIFT 7
#define BKT_NODES 128
#define BKT_CAP 4096   // LDS staging cap; overflow -> direct-write fallback
#define EPB 8192       // edges per block in hist/group passes

typedef _Float16 f16x8 __attribute__((ext_vector_type(8)));
typedef float f32x4 __attribute__((ext_vector_type(4)));

// ---------------- phase A: per-(bucket,block) histogram ----------------
__global__ __launch_bounds__(1024) void block_hist_kernel(
    const int* __restrict__ dst, int* __restrict__ hist, int E, int NBKT, int NBLK) {
  __shared__ int lh[1024];  // >= NBKT
  const int t = threadIdx.x;
  const int blk = blockIdx.x;
  for (int k = t; k < NBKT; k += 1024) lh[k] = 0;
  __syncthreads();
  const int e0 = blk * EPB;
  const int e1 = min(e0 + EPB, E);
  for (int e = e0 + t; e < e1; e += 1024) atomicAdd(&lh[dst[e] >> BKT_SHIFT], 1);
  __syncthreads();
  for (int k = t; k < NBKT; k += 1024) hist[k * NBLK + blk] = lh[k];
}

// ---------------- phase B1: per-bucket row scan (grid-parallel) ----------
__global__ __launch_bounds__(256) void row_scan_kernel(
    const int* __restrict__ hist, int* __restrict__ ebase, int* __restrict__ btot,
    int NBLK) {
  __shared__ int sh[256];
  const int k = blockIdx.x;
  const int t = threadIdx.x;
  int v = (t < NBLK) ? hist[(long)k * NBLK + t] : 0;
  sh[t] = v;
  __syncthreads();
  for (int s = 1; s < 256; s <<= 1) {
    int add = (t >= s) ? sh[t - s] : 0;
    __syncthreads();
    sh[t] += add;
    __syncthreads();
  }
  if (t < NBLK) ebase[(long)k * NBLK + t] = sh[t] - v;  // row-local exclusive
  if (t == 255) btot[k] = sh[255];
}

// ---------------- phase B2: scan bucket totals (single block, LDS-only) --
__global__ __launch_bounds__(1024) void bucket_scan_kernel(
    const int* __restrict__ btot, int* __restrict__ bbase, int E, int NBKT) {
  __shared__ int sh[1024];
  const int t = threadIdx.x;
  int v = (t < NBKT) ? btot[t] : 0;
  sh[t] = v;
  __syncthreads();
  for (int s = 1; s < 1024; s <<= 1) {
    int add = (t >= s) ? sh[t - s] : 0;
    __syncthreads();
    sh[t] += add;
    __syncthreads();
  }
  if (t < NBKT) bbase[t] = sh[t] - v;
  if (t == 0) bbase[NBKT] = E;
}

// ---------------- phase C: group edges by bucket (sequential runs) --------
__global__ __launch_bounds__(1024) void group_kernel(
    const int* __restrict__ src, const int* __restrict__ dst,
    const int* __restrict__ bbase, const int* __restrict__ ebase,
    unsigned int* __restrict__ grouped, int E, int NBKT, int NBLK) {
  __shared__ int lcur[1024];
  const int t = threadIdx.x;
  const int blk = blockIdx.x;
  for (int k = t; k < NBKT; k += 1024)
    lcur[k] = bbase[k] + ebase[(long)k * NBLK + blk];
  __syncthreads();
  const int e0 = blk * EPB;
  const int e1 = min(e0 + EPB, E);
  for (int e = e0 + t; e < e1; e += 1024) {
    int d = dst[e];
    int b = d >> BKT_SHIFT;
    int pos = atomicAdd(&lcur[b], 1);
    grouped[pos] = ((unsigned int)(d & (BKT_NODES - 1)) << 17) | (unsigned int)src[e];
  }
}

// ---------------- phase D: per-bucket CSR finalize + ends + dis ----------
__global__ __launch_bounds__(256) void bucket_build_kernel(
    const unsigned int* __restrict__ grouped, const int* __restrict__ bbase,
    int* __restrict__ csr_src, int* __restrict__ ends, float* __restrict__ dis, int N) {
  __shared__ int lcnt[BKT_NODES];
  __shared__ int lsum[BKT_NODES];
  __shared__ int lcur[BKT_NODES];
  __shared__ int stage[BKT_CAP];
  const int b = blockIdx.x;
  const int t = threadIdx.x;
  const int node0 = b << BKT_SHIFT;
  const int nn = min(BKT_NODES, N - node0);
  const int base = bbase[b];
  const int m = bbase[b + 1] - base;

  if (t < BKT_NODES) lcnt[t] = 0;
  __syncthreads();
  for (int i = t; i < m; i += 256) atomicAdd(&lcnt[grouped[base + i] >> 17], 1);
  __syncthreads();
  if (t < BKT_NODES) lsum[t] = lcnt[t];
  __syncthreads();
  for (int s = 1; s < BKT_NODES; s <<= 1) {
    int add = 0;
    if (t < BKT_NODES && t >= s) add = lsum[t - s];
    __syncthreads();
    if (t < BKT_NODES) lsum[t] += add;
    __syncthreads();
  }
  if (t < nn) {
    ends[node0 + t] = base + lsum[t];                      // global inclusive end
    dis[node0 + t] = 1.0f / sqrtf((float)(lcnt[t] + 1));   // +1 self loop
    lcur[t] = lsum[t] - lcnt[t];                           // local exclusive cursor
  }
  __syncthreads();
  if (m <= BKT_CAP) {
    for (int i = t; i < m; i += 256) {
      unsigned int v = grouped[base + i];
      int p = atomicAdd(&lcur[v >> 17], 1);
      stage[p] = (int)(v & 0x1FFFFu);
    }
    __syncthreads();
    for (int i = t; i < m; i += 256) csr_src[base + i] = stage[i];
  } else {  // statistically never; correctness fallback
    for (int i = t; i < m; i += 256) {
      unsigned int v = grouped[base + i];
      int p = atomicAdd(&lcur[v >> 17], 1);
      csr_src[base + p] = (int)(v & 0x1FFFFu);
    }
  }
}

// ------- MFMA GEMM: C[N,64] = fp16( (H[N,K] @ W[K,64]) * dis[row] ) -----
// 64 rows/block, 256 thr = 4 waves; wave w owns rows 16w..16w+15.
// Whole K staged: Hs[64][K] fp16, Ws[64][K] fp16 (= W^T), both XOR-swizzled.

template <int K, typename Tin>
__global__ __launch_bounds__(256) void gemm_mfma_kernel(
    const Tin* __restrict__ H, const float* __restrict__ W,
    const float* __restrict__ dis, __half* __restrict__ C, int N) {
  __shared__ __align__(16) __half Hs[64 * K];
  __shared__ __align__(16) __half Ws[64 * K];
  const int t = threadIdx.x;
  const int rowBase = blockIdx.x * 64;

  // ---- stage H (cast to fp16, swizzled) ----
  if constexpr (sizeof(Tin) == 4) {
    const int NF4 = 64 * K / 4;
#pragma unroll
    for (int i = 0; i < NF4 / 256; ++i) {
      int f = t + i * 256;
      int row = f / (K / 4);
      int c4 = f % (K / 4);
      int gr = rowBase + row;
      float4 v = make_float4(0.f, 0.f, 0.f, 0.f);
      if (gr < N) v = *reinterpret_cast<const float4*>(H + (long)gr * K + c4 * 4);
      union { uint2 u; __half2 h[2]; } pk;
      pk.h[0] = __floats2half2_rn(v.x, v.y);
      pk.h[1] = __floats2half2_rn(v.z, v.w);
      int byte = (row * K + c4 * 4) * 2;
      byte ^= (row & 7) << 4;
      *reinterpret_cast<uint2*>(reinterpret_cast<char*>(Hs) + byte) = pk.u;
    }
  } else {
    const int NC = 64 * K / 8;
#pragma unroll
    for (int i = 0; i < NC / 256; ++i) {
      int f = t + i * 256;
      int row = f / (K / 8);
      int c8 = f % (K / 8);
      int gr = rowBase + row;
      uint4 v = make_uint4(0u, 0u, 0u, 0u);
      if (gr < N) v = *reinterpret_cast<const uint4*>(H + (long)gr * K + c8 * 8);
      int byte = (row * K + c8 * 8) * 2;
      byte ^= (row & 7) << 4;
      *reinterpret_cast<uint4*>(reinterpret_cast<char*>(Hs) + byte) = v;
    }
  }

  // ---- stage W^T (transpose via half2 k-pairs, swizzled) ----
  {
    const int NU = (K / 2) * 16;  // (k-pair, col-quad) units
#pragma unroll
    for (int i = 0; i < NU / 256; ++i) {
      int u = t + i * 256;
      int kp = u >> 4;
      int cq = u & 15;
      const float4 w0 = *reinterpret_cast<const float4*>(W + (long)(2 * kp) * 64 + cq * 4);
      const float4 w1 = *reinterpret_cast<const float4*>(W + (long)(2 * kp + 1) * 64 + cq * 4);
#pragma unroll
      for (int j = 0; j < 4; ++j) {
        int c = cq * 4 + j;
        __half2 p = __floats2half2_rn((&w0.x)[j], (&w1.x)[j]);
        int byte = (c * K + 2 * kp) * 2;
        byte ^= (c & 7) << 4;
        *reinterpret_cast<__half2*>(reinterpret_cast<char*>(Ws) + byte) = p;
      }
    }
  }
  __syncthreads();

  // ---- MFMA: wave computes 16 rows x 64 cols ----
  const int w = t >> 6;
  const int l = t & 63;
  const int r = l & 15;
  const int g = l >> 4;
  const int rowL = 16 * w + r;
  f32x4 acc[4] = {{0.f, 0.f, 0.f, 0.f}, {0.f, 0.f, 0.f, 0.f},
                  {0.f, 0.f, 0.f, 0.f}, {0.f, 0.f, 0.f, 0.f}};
#pragma unroll
  for (int s = 0; s < K / 32; ++s) {
    int abyte = (rowL * K + s * 32 + g * 8) * 2;
    abyte ^= (rowL & 7) << 4;
    f16x8 afrag = *reinterpret_cast<const f16x8*>(reinterpret_cast<const char*>(Hs) + abyte);
#pragma unroll
    for (int n = 0; n < 4; ++n) {
      int col = n * 16 + r;
      int bbyte = (col * K + s * 32 + g * 8) * 2;
      bbyte ^= (col & 7) << 4;
      f16x8 bfrag = *reinterpret_cast<const f16x8*>(reinterpret_cast<const char*>(Ws) + bbyte);
      acc[n] = __builtin_amdgcn_mfma_f32_16x16x32_f16(afrag, bfrag, acc[n], 0, 0, 0);
    }
  }

  // ---- epilogue: scale by dis[row], round to fp16 ----
  const int outRow0 = rowBase + 16 * w + 4 * g;
#pragma unroll
  for (int j = 0; j < 4; ++j) {
    int row = outRow0 + j;
    if (row < N) {
      float dv = dis[row];
#pragma unroll
      for (int n = 0; n < 4; ++n) {
        C[(long)row * 64 + n * 16 + r] = __float2half(acc[n][j] * dv);
      }
    }
  }
}

// -------- aggregation: CSR, 16 lanes/node, 4 nodes/wave, deep ILP --------
// Lane (g,c) owns cols 4c..4c+3 of node d=wid*4+g. Chunks 0+1 (32 edges)
// fully staged: idx prefetched, 32 row-loads issued before ANY accumulate
// (pad lanes clamp to row d = L1-hot). Dynamic tail for degree>32 only.

__device__ __forceinline__ float4 h4_to_f4(uint2 u) {
  const __half2 lo = *reinterpret_cast<const __half2*>(&u.x);
  const __half2 hi = *reinterpret_cast<const __half2*>(&u.y);
  const float2 flo = __half22float2(lo);
  const float2 fhi = __half22float2(hi);
  return make_float4(flo.x, flo.y, fhi.x, fhi.y);
}

__global__ __launch_bounds__(256) void aggregate_kernel(
    const __half* __restrict__ Ts, const int* __restrict__ csr_src,
    const int* __restrict__ ends, const float* __restrict__ dis,
    const float* __restrict__ bias, __half* __restrict__ O, int N) {
  const int wid = (blockIdx.x * 256 + threadIdx.x) >> 6;
  const int l = threadIdx.x & 63;
  const int g = l >> 4;         // node within wave quad
  const int c = l & 15;         // uint2 column of the 128B row
  const int d0 = wid * 4 + g;
  const bool valid = d0 < N;
  const int d = valid ? d0 : (N - 1);   // safe row for pad lanes
  const int beg = valid ? ((d0 == 0) ? 0 : ends[d0 - 1]) : 0;
  const int m = valid ? (ends[d0] - beg) : 0;   // group-uniform per valid group
  const uint2* Tv = (const uint2*)Ts;

  // self loop (pre-scaled by dis[d])
  float4 a = h4_to_f4(Tv[(long)d * 16 + c]);

  // wave-uniform outer trip count so shfl stays convergent
  int mmax = m;
  mmax = max(mmax, __shfl_xor(mmax, 16, 64));
  mmax = max(mmax, __shfl_xor(mmax, 32, 64));

  const int gbase = l & 48;     // first lane of this group

  // ---- prefetch indices for chunks 0 and 1 ----
  int idx0 = (c < m) ? csr_src[beg + c] : 0;
  int idx1 = (16 + c < m) ? csr_src[beg + 16 + c] : 0;

  // ---- stage all 32 row loads before accumulating ----
  uint2 fr0[16], fr1[16];
  const bool has0 = (mmax > 0), has1 = (mmax > 16);
  if (has0) {
#pragma unroll
    for (int j = 0; j < 16; ++j) {
      int s = __shfl(idx0, gbase + j, 64);
      s = (j < m) ? s : d;              // pad -> own row (L1-hot)
      fr0[j] = Tv[(long)s * 16 + c];
    }
  }
  if (has1) {
#pragma unroll
    for (int j = 0; j < 16; ++j) {
      int s = __shfl(idx1, gbase + j, 64);
      s = (j + 16 < m) ? s : d;
      fr1[j] = Tv[(long)s * 16 + c];
    }
  }
  if (has0) {
#pragma unroll
    for (int j = 0; j < 16; ++j) {
      if (j < m) {
        float4 f = h4_to_f4(fr0[j]);
        a.x += f.x; a.y += f.y; a.z += f.z; a.w += f.w;
      }
    }
  }
  if (has1) {
#pragma unroll
    for (int j = 0; j < 16; ++j) {
      if (j + 16 < m) {
        float4 f = h4_to_f4(fr1[j]);
        a.x += f.x; a.y += f.y; a.z += f.z; a.w += f.w;
      }
    }
  }

  // ---- dynamic tail (degree > 32; Poisson(16) => rare) ----
  for (int base = 32; base < mmax; base += 16) {
    const int take = m - base;
    int idx = (base + c < m) ? csr_src[beg + base + c] : 0;
    uint2 fr[16];
#pragma unroll
    for (int j = 0; j < 16; ++j) {
      int s = __shfl(idx, gbase + j, 64);
      s = (j < take) ? s : d;
      fr[j] = Tv[(long)s * 16 + c];
    }
#pragma unroll
    for (int j = 0; j < 16; ++j) {
      if (j < take) {
        float4 f = h4_to_f4(fr[j]);
        a.x += f.x; a.y += f.y; a.z += f.z; a.w += f.w;
      }
    }
  }

  if (valid) {
    const float dd = dis[d0];
    const float4 b4 = ((const float4*)bias)[c];
    union { uint2 uu; __half2 h[2]; } pk;
    pk.h[0] = __floats2half2_rn(fmaxf(a.x * dd + b4.x, 0.f),
                                fmaxf(a.y * dd + b4.y, 0.f));
    pk.h[1] = __floats2half2_rn(fmaxf(a.z * dd + b4.z, 0.f),
                                fmaxf(a.w * dd + b4.w, 0.f));
    ((uint2*)O)[(long)d0 * 16 + c] = pk.uu;
  }
}

// ---------------- pooling (logits fused) ----------------

__global__ __launch_bounds__(256) void pool_kernel(
    const __half* __restrict__ h3, const float* __restrict__ clo,
    const float* __restrict__ Wc, const float* __restrict__ bc,
    const int* __restrict__ batch, const float* __restrict__ Wa1,
    const float* __restrict__ ba1, const float* __restrict__ Wa2,
    const float* __restrict__ ba2, float* __restrict__ out, int N) {
  __shared__ int sLo, sHi;
  __shared__ float red[256];
  __shared__ float Vs[4][64];
  __shared__ float sse[4];
  __shared__ float gv[64];
  __shared__ float am[16];
  const int g = blockIdx.x;
  const int t = threadIdx.x;
  if (t == 0) {
    int lo = 0, hi = N;
    while (lo < hi) { int mid = (lo + hi) >> 1; if (batch[mid] < g) lo = mid + 1; else hi = mid; }
    sLo = lo;
    lo = 0; hi = N;
    while (lo < hi) { int mid = (lo + hi) >> 1; if (batch[mid] < g + 1) lo = mid + 1; else hi = mid; }
    sHi = lo;
  }
  __syncthreads();
  const int lo = sLo, hi = sHi;

  // logits computed inline: lb(i) = dot(clo[i,0:8], Wc) + bc
  float wc[8];
#pragma unroll
  for (int k = 0; k < 8; ++k) wc[k] = Wc[k];
  const float bc0 = bc[0];

  float lm = -1e30f;
  for (int i = lo + t; i < hi; i += 256) {
    const float4 c0 = *reinterpret_cast<const float4*>(clo + (long)i * 8);
    const float4 c1 = *reinterpret_cast<const float4*>(clo + (long)i * 8 + 4);
    float s = bc0 + c0.x * wc[0] + c0.y * wc[1] + c0.z * wc[2] + c0.w * wc[3]
                  + c1.x * wc[4] + c1.y * wc[5] + c1.z * wc[6] + c1.w * wc[7];
    lm = fmaxf(lm, s);
  }
  red[t] = lm;
  __syncthreads();
  for (int s = 128; s > 0; s >>= 1) {
    if (t < s) red[t] = fmaxf(red[t], red[t + s]);
    __syncthreads();
  }
  const float m = red[0];

  const int f = t & 63, sub = t >> 6;
  float vacc = 0.f, seacc = 0.f;
  for (int i = lo + sub; i < hi; i += 4) {
    const float4 c0 = *reinterpret_cast<const float4*>(clo + (long)i * 8);
    const float4 c1 = *reinterpret_cast<const float4*>(clo + (long)i * 8 + 4);
    float s = bc0 + c0.x * wc[0] + c0.y * wc[1] + c0.z * wc[2] + c0.w * wc[3]
                  + c1.x * wc[4] + c1.y * wc[5] + c1.z * wc[6] + c1.w * wc[7];
    float e = expf(s - m);
    seacc += e;
    vacc += e * __half2float(h3[(long)i * 64 + f]);
  }
  Vs[sub][f] = vacc;
  if (f == 0) sse[sub] = seacc;
  __syncthreads();
  if (t < 64) {
    float se = sse[0] + sse[1] + sse[2] + sse[3];
    float v = Vs[0][f] + Vs[1][f] + Vs[2][f] + Vs[3][f];
    gv[f] = (se > 0.f) ? v / se : 0.f;
  }
  __syncthreads();
  if (t < 16) {
    float a = ba1[t];
#pragma unroll
    for (int k2 = 0; k2 < 64; ++k2) a += gv[k2] * Wa1[k2 * 16 + t];
    am[t] = a > 0.f ? a : 0.f;
  }
  __syncthreads();
  if (t == 0) {
    float o = ba2[0];
#pragma unroll
    for (int j = 0; j < 16; ++j) o += am[j] * Wa2[j];
    out[g] = o;
  }
}

// ---------------- launcher ----------------

extern "C" void kernel_launch(void* const* d_in, const int* in_sizes, int n_in,
                              void* d_out, int out_size, void* d_ws, size_t ws_size,
                              hipStream_t stream) {
  const float* x   = (const float*)d_in[0];
  const float* clo = (const float*)d_in[1];
  const float* W1  = (const float*)d_in[2];
  const float* b1  = (const float*)d_in[3];
  const float* W2  = (const float*)d_in[4];
  const float* b2  = (const float*)d_in[5];
  const float* W3  = (const float*)d_in[6];
  const float* b3  = (const float*)d_in[7];
  const float* Wc  = (const float*)d_in[8];
  const float* bc  = (const float*)d_in[9];
  const float* Wa1 = (const float*)d_in[10];
  const float* ba1 = (const float*)d_in[11];
  const float* Wa2 = (const float*)d_in[12];
  const float* ba2 = (const float*)d_in[13];
  const int* edge  = (const int*)d_in[14];
  const int* batch = (const int*)d_in[15];
  float* out = (float*)d_out;

  const int N = in_sizes[15];        // 100000
  const int E = in_sizes[14] / 2;    // 1600000
  const int G = out_size;            // 256
  const int NBKT = (N + BKT_NODES - 1) >> BKT_SHIFT;  // 782 (<=1024)
  const int NBLK = (E + EPB - 1) / EPB;               // 196 (<=256)

  const int* src = edge;
  const int* dst = edge + E;

  char* p = (char*)d_ws;
  auto alloc = [&](size_t bytes) -> char* {
    char* r = p;
    p += (bytes + 255) & ~(size_t)255;
    return r;
  };
  __half* tsbuf         = (__half*)alloc((size_t)N * 64 * sizeof(__half));
  __half* bufH          = (__half*)alloc((size_t)N * 64 * sizeof(__half));
  int*   csr_src        = (int*)  alloc((size_t)E * sizeof(int));
  unsigned int* grouped = (unsigned int*)alloc((size_t)E * sizeof(unsigned int));
  int*   hist           = (int*)  alloc((size_t)NBKT * NBLK * sizeof(int));
  int*   ebase          = (int*)  alloc((size_t)NBKT * NBLK * sizeof(int));
  int*   btot           = (int*)  alloc((size_t)NBKT * sizeof(int));
  int*   bbase          = (int*)  alloc((size_t)(NBKT + 1) * sizeof(int));
  int*   ends           = (int*)  alloc((size_t)N * sizeof(int));
  float* dis            = (float*)alloc((size_t)N * sizeof(float));
  (void)ws_size; (void)n_in;

  block_hist_kernel<<<NBLK, 1024, 0, stream>>>(dst, hist, E, NBKT, NBLK);
  row_scan_kernel<<<NBKT, 256, 0, stream>>>(hist, ebase, btot, NBLK);
  bucket_scan_kernel<<<1, 1024, 0, stream>>>(btot, bbase, E, NBKT);
  group_kernel<<<NBLK, 1024, 0, stream>>>(src, dst, bbase, ebase, grouped, E, NBKT, NBLK);
  bucket_build_kernel<<<NBKT, 256, 0, stream>>>(grouped, bbase, csr_src, ends, dis, N);

  const int gGemm = (N + 63) / 64;
  const int gAgg  = (N + 15) / 16;   // 16 nodes per 256-thread block

  gemm_mfma_kernel<128, float><<<gGemm, 256, 0, stream>>>(x, W1, dis, tsbuf, N);
  aggregate_kernel<<<gAgg, 256, 0, stream>>>(tsbuf, csr_src, ends, dis, b1, bufH, N);
  gemm_mfma_kernel<64, __half><<<gGemm, 256, 0, stream>>>(bufH, W2, dis, tsbuf, N);
  aggregate_kernel<<<gAgg, 256, 0, stream>>>(tsbuf, csr_src, ends, dis, b2, bufH, N);
  gemm_mfma_kernel<64, __half><<<gGemm, 256, 0, stream>>>(bufH, W3, dis, tsbuf, N);
  aggregate_kernel<<<gAgg, 256, 0, stream>>>(tsbuf, csr_src, ends, dis, b3, bufH, N);

  pool_kernel<<<G, 256, 0, stream>>>(bufH, clo, Wc, bc, batch, Wa1, ba1, Wa2, ba2, out, N);
}

// Round 10
// 307.515 us; speedup vs baseline: 1.2618x; 1.0606x over previous
//
#include <hip/hip_runtime.h>
#include <hip/hip_fp16.h>
#include <math.h>

// R7: radix CSR build. R12: fp16 gather table. R13: MFMA GEMM. R16/R17:
// 16-lanes/node aggregate + 32-deep ILP staging (~6TB/s effective =
// random-gather fabric ceiling). R19: revert of R18's global-atomic deg
// (lesson: random fine-grained atomics lose), kept logits->pool fusion.
// 326.1us.
// R20 (this round): pool_kernel 256->1024 threads. R19 evidence: pool
// 41.4us @ occupancy 8.4% (4 waves/CU), HBM 2.5%, VALU 11% -- pure
// unhidden latency, ~97 serial iterations of load+expf chain per thread.
// 16 waves/block + 16 sub-groups => 4x fewer iterations, 4x waves/CU.

#define BKT_SHIFT 7
#define BKT_NODES 128
#define BKT_CAP 4096   // LDS staging cap; overflow -> direct-write fallback
#define EPB 8192       // edges per block in hist/group passes

typedef _Float16 f16x8 __attribute__((ext_vector_type(8)));
typedef float f32x4 __attribute__((ext_vector_type(4)));

// ---------------- phase A: per-(bucket,block) histogram ----------------
__global__ __launch_bounds__(1024) void block_hist_kernel(
    const int* __restrict__ dst, int* __restrict__ hist, int E, int NBKT, int NBLK) {
  __shared__ int lh[1024];  // >= NBKT
  const int t = threadIdx.x;
  const int blk = blockIdx.x;
  for (int k = t; k < NBKT; k += 1024) lh[k] = 0;
  __syncthreads();
  const int e0 = blk * EPB;
  const int e1 = min(e0 + EPB, E);
  for (int e = e0 + t; e < e1; e += 1024) atomicAdd(&lh[dst[e] >> BKT_SHIFT], 1);
  __syncthreads();
  for (int k = t; k < NBKT; k += 1024) hist[k * NBLK + blk] = lh[k];
}

// ---------------- phase B1: per-bucket row scan (grid-parallel) ----------
__global__ __launch_bounds__(256) void row_scan_kernel(
    const int* __restrict__ hist, int* __restrict__ ebase, int* __restrict__ btot,
    int NBLK) {
  __shared__ int sh[256];
  const int k = blockIdx.x;
  const int t = threadIdx.x;
  int v = (t < NBLK) ? hist[(long)k * NBLK + t] : 0;
  sh[t] = v;
  __syncthreads();
  for (int s = 1; s < 256; s <<= 1) {
    int add = (t >= s) ? sh[t - s] : 0;
    __syncthreads();
    sh[t] += add;
    __syncthreads();
  }
  if (t < NBLK) ebase[(long)k * NBLK + t] = sh[t] - v;  // row-local exclusive
  if (t == 255) btot[k] = sh[255];
}

// ---------------- phase B2: scan bucket totals (single block, LDS-only) --
__global__ __launch_bounds__(1024) void bucket_scan_kernel(
    const int* __restrict__ btot, int* __restrict__ bbase, int E, int NBKT) {
  __shared__ int sh[1024];
  const int t = threadIdx.x;
  int v = (t < NBKT) ? btot[t] : 0;
  sh[t] = v;
  __syncthreads();
  for (int s = 1; s < 1024; s <<= 1) {
    int add = (t >= s) ? sh[t - s] : 0;
    __syncthreads();
    sh[t] += add;
    __syncthreads();
  }
  if (t < NBKT) bbase[t] = sh[t] - v;
  if (t == 0) bbase[NBKT] = E;
}

// ---------------- phase C: group edges by bucket (sequential runs) --------
__global__ __launch_bounds__(1024) void group_kernel(
    const int* __restrict__ src, const int* __restrict__ dst,
    const int* __restrict__ bbase, const int* __restrict__ ebase,
    unsigned int* __restrict__ grouped, int E, int NBKT, int NBLK) {
  __shared__ int lcur[1024];
  const int t = threadIdx.x;
  const int blk = blockIdx.x;
  for (int k = t; k < NBKT; k += 1024)
    lcur[k] = bbase[k] + ebase[(long)k * NBLK + blk];
  __syncthreads();
  const int e0 = blk * EPB;
  const int e1 = min(e0 + EPB, E);
  for (int e = e0 + t; e < e1; e += 1024) {
    int d = dst[e];
    int b = d >> BKT_SHIFT;
    int pos = atomicAdd(&lcur[b], 1);
    grouped[pos] = ((unsigned int)(d & (BKT_NODES - 1)) << 17) | (unsigned int)src[e];
  }
}

// ---------------- phase D: per-bucket CSR finalize + ends + dis ----------
__global__ __launch_bounds__(256) void bucket_build_kernel(
    const unsigned int* __restrict__ grouped, const int* __restrict__ bbase,
    int* __restrict__ csr_src, int* __restrict__ ends, float* __restrict__ dis, int N) {
  __shared__ int lcnt[BKT_NODES];
  __shared__ int lsum[BKT_NODES];
  __shared__ int lcur[BKT_NODES];
  __shared__ int stage[BKT_CAP];
  const int b = blockIdx.x;
  const int t = threadIdx.x;
  const int node0 = b << BKT_SHIFT;
  const int nn = min(BKT_NODES, N - node0);
  const int base = bbase[b];
  const int m = bbase[b + 1] - base;

  if (t < BKT_NODES) lcnt[t] = 0;
  __syncthreads();
  for (int i = t; i < m; i += 256) atomicAdd(&lcnt[grouped[base + i] >> 17], 1);
  __syncthreads();
  if (t < BKT_NODES) lsum[t] = lcnt[t];
  __syncthreads();
  for (int s = 1; s < BKT_NODES; s <<= 1) {
    int add = 0;
    if (t < BKT_NODES && t >= s) add = lsum[t - s];
    __syncthreads();
    if (t < BKT_NODES) lsum[t] += add;
    __syncthreads();
  }
  if (t < nn) {
    ends[node0 + t] = base + lsum[t];                      // global inclusive end
    dis[node0 + t] = 1.0f / sqrtf((float)(lcnt[t] + 1));   // +1 self loop
    lcur[t] = lsum[t] - lcnt[t];                           // local exclusive cursor
  }
  __syncthreads();
  if (m <= BKT_CAP) {
    for (int i = t; i < m; i += 256) {
      unsigned int v = grouped[base + i];
      int p = atomicAdd(&lcur[v >> 17], 1);
      stage[p] = (int)(v & 0x1FFFFu);
    }
    __syncthreads();
    for (int i = t; i < m; i += 256) csr_src[base + i] = stage[i];
  } else {  // statistically never; correctness fallback
    for (int i = t; i < m; i += 256) {
      unsigned int v = grouped[base + i];
      int p = atomicAdd(&lcur[v >> 17], 1);
      csr_src[base + p] = (int)(v & 0x1FFFFu);
    }
  }
}

// ------- MFMA GEMM: C[N,64] = fp16( (H[N,K] @ W[K,64]) * dis[row] ) -----
// 64 rows/block, 256 thr = 4 waves; wave w owns rows 16w..16w+15.
// Whole K staged: Hs[64][K] fp16, Ws[64][K] fp16 (= W^T), both XOR-swizzled.

template <int K, typename Tin>
__global__ __launch_bounds__(256) void gemm_mfma_kernel(
    const Tin* __restrict__ H, const float* __restrict__ W,
    const float* __restrict__ dis, __half* __restrict__ C, int N) {
  __shared__ __align__(16) __half Hs[64 * K];
  __shared__ __align__(16) __half Ws[64 * K];
  const int t = threadIdx.x;
  const int rowBase = blockIdx.x * 64;

  // ---- stage H (cast to fp16, swizzled) ----
  if constexpr (sizeof(Tin) == 4) {
    const int NF4 = 64 * K / 4;
#pragma unroll
    for (int i = 0; i < NF4 / 256; ++i) {
      int f = t + i * 256;
      int row = f / (K / 4);
      int c4 = f % (K / 4);
      int gr = rowBase + row;
      float4 v = make_float4(0.f, 0.f, 0.f, 0.f);
      if (gr < N) v = *reinterpret_cast<const float4*>(H + (long)gr * K + c4 * 4);
      union { uint2 u; __half2 h[2]; } pk;
      pk.h[0] = __floats2half2_rn(v.x, v.y);
      pk.h[1] = __floats2half2_rn(v.z, v.w);
      int byte = (row * K + c4 * 4) * 2;
      byte ^= (row & 7) << 4;
      *reinterpret_cast<uint2*>(reinterpret_cast<char*>(Hs) + byte) = pk.u;
    }
  } else {
    const int NC = 64 * K / 8;
#pragma unroll
    for (int i = 0; i < NC / 256; ++i) {
      int f = t + i * 256;
      int row = f / (K / 8);
      int c8 = f % (K / 8);
      int gr = rowBase + row;
      uint4 v = make_uint4(0u, 0u, 0u, 0u);
      if (gr < N) v = *reinterpret_cast<const uint4*>(H + (long)gr * K + c8 * 8);
      int byte = (row * K + c8 * 8) * 2;
      byte ^= (row & 7) << 4;
      *reinterpret_cast<uint4*>(reinterpret_cast<char*>(Hs) + byte) = v;
    }
  }

  // ---- stage W^T (transpose via half2 k-pairs, swizzled) ----
  {
    const int NU = (K / 2) * 16;  // (k-pair, col-quad) units
#pragma unroll
    for (int i = 0; i < NU / 256; ++i) {
      int u = t + i * 256;
      int kp = u >> 4;
      int cq = u & 15;
      const float4 w0 = *reinterpret_cast<const float4*>(W + (long)(2 * kp) * 64 + cq * 4);
      const float4 w1 = *reinterpret_cast<const float4*>(W + (long)(2 * kp + 1) * 64 + cq * 4);
#pragma unroll
      for (int j = 0; j < 4; ++j) {
        int c = cq * 4 + j;
        __half2 p = __floats2half2_rn((&w0.x)[j], (&w1.x)[j]);
        int byte = (c * K + 2 * kp) * 2;
        byte ^= (c & 7) << 4;
        *reinterpret_cast<__half2*>(reinterpret_cast<char*>(Ws) + byte) = p;
      }
    }
  }
  __syncthreads();

  // ---- MFMA: wave computes 16 rows x 64 cols ----
  const int w = t >> 6;
  const int l = t & 63;
  const int r = l & 15;
  const int g = l >> 4;
  const int rowL = 16 * w + r;
  f32x4 acc[4] = {{0.f, 0.f, 0.f, 0.f}, {0.f, 0.f, 0.f, 0.f},
                  {0.f, 0.f, 0.f, 0.f}, {0.f, 0.f, 0.f, 0.f}};
#pragma unroll
  for (int s = 0; s < K / 32; ++s) {
    int abyte = (rowL * K + s * 32 + g * 8) * 2;
    abyte ^= (rowL & 7) << 4;
    f16x8 afrag = *reinterpret_cast<const f16x8*>(reinterpret_cast<const char*>(Hs) + abyte);
#pragma unroll
    for (int n = 0; n < 4; ++n) {
      int col = n * 16 + r;
      int bbyte = (col * K + s * 32 + g * 8) * 2;
      bbyte ^= (col & 7) << 4;
      f16x8 bfrag = *reinterpret_cast<const f16x8*>(reinterpret_cast<const char*>(Ws) + bbyte);
      acc[n] = __builtin_amdgcn_mfma_f32_16x16x32_f16(afrag, bfrag, acc[n], 0, 0, 0);
    }
  }

  // ---- epilogue: scale by dis[row], round to fp16 ----
  const int outRow0 = rowBase + 16 * w + 4 * g;
#pragma unroll
  for (int j = 0; j < 4; ++j) {
    int row = outRow0 + j;
    if (row < N) {
      float dv = dis[row];
#pragma unroll
      for (int n = 0; n < 4; ++n) {
        C[(long)row * 64 + n * 16 + r] = __float2half(acc[n][j] * dv);
      }
    }
  }
}

// -------- aggregation: CSR, 16 lanes/node, 4 nodes/wave, deep ILP --------
// Lane (g,c) owns cols 4c..4c+3 of node d=wid*4+g. Chunks 0+1 (32 edges)
// fully staged: idx prefetched, 32 row-loads issued before ANY accumulate
// (pad lanes clamp to row d = L1-hot). Dynamic tail for degree>32 only.

__device__ __forceinline__ float4 h4_to_f4(uint2 u) {
  const __half2 lo = *reinterpret_cast<const __half2*>(&u.x);
  const __half2 hi = *reinterpret_cast<const __half2*>(&u.y);
  const float2 flo = __half22float2(lo);
  const float2 fhi = __half22float2(hi);
  return make_float4(flo.x, flo.y, fhi.x, fhi.y);
}

__global__ __launch_bounds__(256) void aggregate_kernel(
    const __half* __restrict__ Ts, const int* __restrict__ csr_src,
    const int* __restrict__ ends, const float* __restrict__ dis,
    const float* __restrict__ bias, __half* __restrict__ O, int N) {
  const int wid = (blockIdx.x * 256 + threadIdx.x) >> 6;
  const int l = threadIdx.x & 63;
  const int g = l >> 4;         // node within wave quad
  const int c = l & 15;         // uint2 column of the 128B row
  const int d0 = wid * 4 + g;
  const bool valid = d0 < N;
  const int d = valid ? d0 : (N - 1);   // safe row for pad lanes
  const int beg = valid ? ((d0 == 0) ? 0 : ends[d0 - 1]) : 0;
  const int m = valid ? (ends[d0] - beg) : 0;   // group-uniform per valid group
  const uint2* Tv = (const uint2*)Ts;

  // self loop (pre-scaled by dis[d])
  float4 a = h4_to_f4(Tv[(long)d * 16 + c]);

  // wave-uniform outer trip count so shfl stays convergent
  int mmax = m;
  mmax = max(mmax, __shfl_xor(mmax, 16, 64));
  mmax = max(mmax, __shfl_xor(mmax, 32, 64));

  const int gbase = l & 48;     // first lane of this group

  // ---- prefetch indices for chunks 0 and 1 ----
  int idx0 = (c < m) ? csr_src[beg + c] : 0;
  int idx1 = (16 + c < m) ? csr_src[beg + 16 + c] : 0;

  // ---- stage all 32 row loads before accumulating ----
  uint2 fr0[16], fr1[16];
  const bool has0 = (mmax > 0), has1 = (mmax > 16);
  if (has0) {
#pragma unroll
    for (int j = 0; j < 16; ++j) {
      int s = __shfl(idx0, gbase + j, 64);
      s = (j < m) ? s : d;              // pad -> own row (L1-hot)
      fr0[j] = Tv[(long)s * 16 + c];
    }
  }
  if (has1) {
#pragma unroll
    for (int j = 0; j < 16; ++j) {
      int s = __shfl(idx1, gbase + j, 64);
      s = (j + 16 < m) ? s : d;
      fr1[j] = Tv[(long)s * 16 + c];
    }
  }
  if (has0) {
#pragma unroll
    for (int j = 0; j < 16; ++j) {
      if (j < m) {
        float4 f = h4_to_f4(fr0[j]);
        a.x += f.x; a.y += f.y; a.z += f.z; a.w += f.w;
      }
    }
  }
  if (has1) {
#pragma unroll
    for (int j = 0; j < 16; ++j) {
      if (j + 16 < m) {
        float4 f = h4_to_f4(fr1[j]);
        a.x += f.x; a.y += f.y; a.z += f.z; a.w += f.w;
      }
    }
  }

  // ---- dynamic tail (degree > 32; Poisson(16) => rare) ----
  for (int base = 32; base < mmax; base += 16) {
    const int take = m - base;
    int idx = (base + c < m) ? csr_src[beg + base + c] : 0;
    uint2 fr[16];
#pragma unroll
    for (int j = 0; j < 16; ++j) {
      int s = __shfl(idx, gbase + j, 64);
      s = (j < take) ? s : d;
      fr[j] = Tv[(long)s * 16 + c];
    }
#pragma unroll
    for (int j = 0; j < 16; ++j) {
      if (j < take) {
        float4 f = h4_to_f4(fr[j]);
        a.x += f.x; a.y += f.y; a.z += f.z; a.w += f.w;
      }
    }
  }

  if (valid) {
    const float dd = dis[d0];
    const float4 b4 = ((const float4*)bias)[c];
    union { uint2 uu; __half2 h[2]; } pk;
    pk.h[0] = __floats2half2_rn(fmaxf(a.x * dd + b4.x, 0.f),
                                fmaxf(a.y * dd + b4.y, 0.f));
    pk.h[1] = __floats2half2_rn(fmaxf(a.z * dd + b4.z, 0.f),
                                fmaxf(a.w * dd + b4.w, 0.f));
    ((uint2*)O)[(long)d0 * 16 + c] = pk.uu;
  }
}

// -------- pooling (logits fused, 1024 thr = 16 waves for latency) --------

__global__ __launch_bounds__(1024) void pool_kernel(
    const __half* __restrict__ h3, const float* __restrict__ clo,
    const float* __restrict__ Wc, const float* __restrict__ bc,
    const int* __restrict__ batch, const float* __restrict__ Wa1,
    const float* __restrict__ ba1, const float* __restrict__ Wa2,
    const float* __restrict__ ba2, float* __restrict__ out, int N) {
  __shared__ int sLo, sHi;
  __shared__ float red[1024];
  __shared__ float Vs[16][64];
  __shared__ float sse[16];
  __shared__ float gv[64];
  __shared__ float am[16];
  const int g = blockIdx.x;
  const int t = threadIdx.x;
  if (t == 0) {
    int lo = 0, hi = N;
    while (lo < hi) { int mid = (lo + hi) >> 1; if (batch[mid] < g) lo = mid + 1; else hi = mid; }
    sLo = lo;
    lo = 0; hi = N;
    while (lo < hi) { int mid = (lo + hi) >> 1; if (batch[mid] < g + 1) lo = mid + 1; else hi = mid; }
    sHi = lo;
  }
  __syncthreads();
  const int lo = sLo, hi = sHi;

  // logits computed inline: lb(i) = dot(clo[i,0:8], Wc) + bc
  float wc[8];
#pragma unroll
  for (int k = 0; k < 8; ++k) wc[k] = Wc[k];
  const float bc0 = bc[0];

  float lm = -1e30f;
  for (int i = lo + t; i < hi; i += 1024) {
    const float4 c0 = *reinterpret_cast<const float4*>(clo + (long)i * 8);
    const float4 c1 = *reinterpret_cast<const float4*>(clo + (long)i * 8 + 4);
    float s = bc0 + c0.x * wc[0] + c0.y * wc[1] + c0.z * wc[2] + c0.w * wc[3]
                  + c1.x * wc[4] + c1.y * wc[5] + c1.z * wc[6] + c1.w * wc[7];
    lm = fmaxf(lm, s);
  }
  red[t] = lm;
  __syncthreads();
  for (int s = 512; s > 0; s >>= 1) {
    if (t < s) red[t] = fmaxf(red[t], red[t + s]);
    __syncthreads();
  }
  const float m = red[0];

  const int f = t & 63, sub = t >> 6;   // 16 sub-groups of one wave each
  float vacc = 0.f, seacc = 0.f;
  for (int i = lo + sub; i < hi; i += 16) {
    const float4 c0 = *reinterpret_cast<const float4*>(clo + (long)i * 8);
    const float4 c1 = *reinterpret_cast<const float4*>(clo + (long)i * 8 + 4);
    float s = bc0 + c0.x * wc[0] + c0.y * wc[1] + c0.z * wc[2] + c0.w * wc[3]
                  + c1.x * wc[4] + c1.y * wc[5] + c1.z * wc[6] + c1.w * wc[7];
    float e = expf(s - m);
    seacc += e;
    vacc += e * __half2float(h3[(long)i * 64 + f]);
  }
  Vs[sub][f] = vacc;
  if (f == 0) sse[sub] = seacc;
  __syncthreads();
  if (t < 64) {
    float se = 0.f, v = 0.f;
#pragma unroll
    for (int s2 = 0; s2 < 16; ++s2) { se += sse[s2]; v += Vs[s2][f]; }
    gv[f] = (se > 0.f) ? v / se : 0.f;
  }
  __syncthreads();
  if (t < 16) {
    float a = ba1[t];
#pragma unroll
    for (int k2 = 0; k2 < 64; ++k2) a += gv[k2] * Wa1[k2 * 16 + t];
    am[t] = a > 0.f ? a : 0.f;
  }
  __syncthreads();
  if (t == 0) {
    float o = ba2[0];
#pragma unroll
    for (int j = 0; j < 16; ++j) o += am[j] * Wa2[j];
    out[g] = o;
  }
}

// ---------------- launcher ----------------

extern "C" void kernel_launch(void* const* d_in, const int* in_sizes, int n_in,
                              void* d_out, int out_size, void* d_ws, size_t ws_size,
                              hipStream_t stream) {
  const float* x   = (const float*)d_in[0];
  const float* clo = (const float*)d_in[1];
  const float* W1  = (const float*)d_in[2];
  const float* b1  = (const float*)d_in[3];
  const float* W2  = (const float*)d_in[4];
  const float* b2  = (const float*)d_in[5];
  const float* W3  = (const float*)d_in[6];
  const float* b3  = (const float*)d_in[7];
  const float* Wc  = (const float*)d_in[8];
  const float* bc  = (const float*)d_in[9];
  const float* Wa1 = (const float*)d_in[10];
  const float* ba1 = (const float*)d_in[11];
  const float* Wa2 = (const float*)d_in[12];
  const float* ba2 = (const float*)d_in[13];
  const int* edge  = (const int*)d_in[14];
  const int* batch = (const int*)d_in[15];
  float* out = (float*)d_out;

  const int N = in_sizes[15];        // 100000
  const int E = in_sizes[14] / 2;    // 1600000
  const int G = out_size;            // 256
  const int NBKT = (N + BKT_NODES - 1) >> BKT_SHIFT;  // 782 (<=1024)
  const int NBLK = (E + EPB - 1) / EPB;               // 196 (<=256)

  const int* src = edge;
  const int* dst = edge + E;

  char* p = (char*)d_ws;
  auto alloc = [&](size_t bytes) -> char* {
    char* r = p;
    p += (bytes + 255) & ~(size_t)255;
    return r;
  };
  __half* tsbuf         = (__half*)alloc((size_t)N * 64 * sizeof(__half));
  __half* bufH          = (__half*)alloc((size_t)N * 64 * sizeof(__half));
  int*   csr_src        = (int*)  alloc((size_t)E * sizeof(int));
  unsigned int* grouped = (unsigned int*)alloc((size_t)E * sizeof(unsigned int));
  int*   hist           = (int*)  alloc((size_t)NBKT * NBLK * sizeof(int));
  int*   ebase          = (int*)  alloc((size_t)NBKT * NBLK * sizeof(int));
  int*   btot           = (int*)  alloc((size_t)NBKT * sizeof(int));
  int*   bbase          = (int*)  alloc((size_t)(NBKT + 1) * sizeof(int));
  int*   ends           = (int*)  alloc((size_t)N * sizeof(int));
  float* dis            = (float*)alloc((size_t)N * sizeof(float));
  (void)ws_size; (void)n_in;

  block_hist_kernel<<<NBLK, 1024, 0, stream>>>(dst, hist, E, NBKT, NBLK);
  row_scan_kernel<<<NBKT, 256, 0, stream>>>(hist, ebase, btot, NBLK);
  bucket_scan_kernel<<<1, 1024, 0, stream>>>(btot, bbase, E, NBKT);
  group_kernel<<<NBLK, 1024, 0, stream>>>(src, dst, bbase, ebase, grouped, E, NBKT, NBLK);
  bucket_build_kernel<<<NBKT, 256, 0, stream>>>(grouped, bbase, csr_src, ends, dis, N);

  const int gGemm = (N + 63) / 64;
  const int gAgg  = (N + 15) / 16;   // 16 nodes per 256-thread block

  gemm_mfma_kernel<128, float><<<gGemm, 256, 0, stream>>>(x, W1, dis, tsbuf, N);
  aggregate_kernel<<<gAgg, 256, 0, stream>>>(tsbuf, csr_src, ends, dis, b1, bufH, N);
  gemm_mfma_kernel<64, __half><<<gGemm, 256, 0, stream>>>(bufH, W2, dis, tsbuf, N);
  aggregate_kernel<<<gAgg, 256, 0, stream>>>(tsbuf, csr_src, ends, dis, b2, bufH, N);
  gemm_mfma_kernel<64, __half><<<gGemm, 256, 0, stream>>>(bufH, W3, dis, tsbuf, N);
  aggregate_kernel<<<gAgg, 256, 0, stream>>>(tsbuf, csr_src, ends, dis, b3, bufH, N);

  pool_kernel<<<G, 1024, 0, stream>>>(bufH, clo, Wc, bc, batch, Wa1, ba1, Wa2, ba2, out, N);
}

// Round 11
// 305.868 us; speedup vs baseline: 1.2686x; 1.0054x over previous
//
#include <hip/hip_runtime.h>
#include <hip/hip_fp16.h>
#include <math.h>

// R7: radix CSR build. R12: fp16 gather table. R13: MFMA GEMM. R16/R17:
// 16-lanes/node aggregate + 32-deep ILP staging (~6TB/s effective =
// random-gather fabric ceiling). R19: logits->pool fusion. R20: pool 1024
// threads (41.4 -> <15us, occupancy fix) -> 307.5us.
// R21 (this round): group_kernel block-local counting sort. Old inner loop
// wrote grouped[pos] with 64 lanes hitting 64 different bucket regions =
// ~64 lines per store instr (8192 line-RMWs/block). New: scatter into LDS
// stage[] sorted by bucket (counts already in hist[k][blk] -> LDS scan),
// then flush runs with 16-lane subgroups = consecutive global addresses.
// Build phase is the dominant remaining block (~110-150us over 5 kernels,
// all <40.5us = fill-masked).

#define BKT_SHIFT 7
#define BKT_NODES 128
#define BKT_CAP 4096   // LDS staging cap; overflow -> direct-write fallback
#define EPB 8192       // edges per block; == group stage capacity (exact)

typedef _Float16 f16x8 __attribute__((ext_vector_type(8)));
typedef float f32x4 __attribute__((ext_vector_type(4)));

// ---------------- phase A: per-(bucket,block) histogram ----------------
__global__ __launch_bounds__(1024) void block_hist_kernel(
    const int* __restrict__ dst, int* __restrict__ hist, int E, int NBKT, int NBLK) {
  __shared__ int lh[1024];  // >= NBKT
  const int t = threadIdx.x;
  const int blk = blockIdx.x;
  for (int k = t; k < NBKT; k += 1024) lh[k] = 0;
  __syncthreads();
  const int e0 = blk * EPB;
  const int e1 = min(e0 + EPB, E);
  for (int e = e0 + t; e < e1; e += 1024) atomicAdd(&lh[dst[e] >> BKT_SHIFT], 1);
  __syncthreads();
  for (int k = t; k < NBKT; k += 1024) hist[k * NBLK + blk] = lh[k];
}

// ---------------- phase B1: per-bucket row scan (grid-parallel) ----------
__global__ __launch_bounds__(256) void row_scan_kernel(
    const int* __restrict__ hist, int* __restrict__ ebase, int* __restrict__ btot,
    int NBLK) {
  __shared__ int sh[256];
  const int k = blockIdx.x;
  const int t = threadIdx.x;
  int v = (t < NBLK) ? hist[(long)k * NBLK + t] : 0;
  sh[t] = v;
  __syncthreads();
  for (int s = 1; s < 256; s <<= 1) {
    int add = (t >= s) ? sh[t - s] : 0;
    __syncthreads();
    sh[t] += add;
    __syncthreads();
  }
  if (t < NBLK) ebase[(long)k * NBLK + t] = sh[t] - v;  // row-local exclusive
  if (t == 255) btot[k] = sh[255];
}

// ---------------- phase B2: scan bucket totals (single block, LDS-only) --
__global__ __launch_bounds__(1024) void bucket_scan_kernel(
    const int* __restrict__ btot, int* __restrict__ bbase, int E, int NBKT) {
  __shared__ int sh[1024];
  const int t = threadIdx.x;
  int v = (t < NBKT) ? btot[t] : 0;
  sh[t] = v;
  __syncthreads();
  for (int s = 1; s < 1024; s <<= 1) {
    int add = (t >= s) ? sh[t - s] : 0;
    __syncthreads();
    sh[t] += add;
    __syncthreads();
  }
  if (t < NBKT) bbase[t] = sh[t] - v;
  if (t == 0) bbase[NBKT] = E;
}

// ------- phase C: group edges by bucket (LDS counting sort + runs) -------
// Scatter payloads into LDS stage sorted by bucket (block-local offsets
// from this block's hist column), then flush each bucket run with 16-lane
// subgroups -> consecutive global addresses (~2 lines/store-instr vs 64).
__global__ __launch_bounds__(1024) void group_kernel(
    const int* __restrict__ src, const int* __restrict__ dst,
    const int* __restrict__ bbase, const int* __restrict__ ebase,
    const int* __restrict__ hist, unsigned int* __restrict__ grouped,
    int E, int NBKT, int NBLK) {
  __shared__ int lsum[1024];
  __shared__ int lbase[1024];
  __shared__ int lcur[1024];
  __shared__ unsigned int stage[EPB];   // 32KB; per-block edges <= EPB exact
  const int t = threadIdx.x;
  const int blk = blockIdx.x;

  int v = (t < NBKT) ? hist[(long)t * NBLK + blk] : 0;
  lsum[t] = v;
  __syncthreads();
  for (int s = 1; s < 1024; s <<= 1) {
    int add = (t >= s) ? lsum[t - s] : 0;
    __syncthreads();
    lsum[t] += add;
    __syncthreads();
  }
  if (t < NBKT) {
    lbase[t] = lsum[t] - v;
    lcur[t] = lsum[t] - v;
  }
  __syncthreads();

  const int e0 = blk * EPB;
  const int e1 = min(e0 + EPB, E);
  for (int e = e0 + t; e < e1; e += 1024) {
    int d = dst[e];
    int k = d >> BKT_SHIFT;
    int p = atomicAdd(&lcur[k], 1);
    stage[p] = ((unsigned int)(d & (BKT_NODES - 1)) << 17) | (unsigned int)src[e];
  }
  __syncthreads();

  // flush: 64 subgroups of 16 lanes; subgroup sg handles buckets sg, sg+64...
  const int sg = t >> 4;
  const int l16 = t & 15;
  for (int k = sg; k < NBKT; k += 64) {
    const int lb = lbase[k];
    const int L = lcur[k] - lb;
    if (L == 0) continue;
    const long gb = (long)bbase[k] + ebase[(long)k * NBLK + blk];
    for (int off = l16; off < L; off += 16)
      grouped[gb + off] = stage[lb + off];
  }
}

// ---------------- phase D: per-bucket CSR finalize + ends + dis ----------
__global__ __launch_bounds__(256) void bucket_build_kernel(
    const unsigned int* __restrict__ grouped, const int* __restrict__ bbase,
    int* __restrict__ csr_src, int* __restrict__ ends, float* __restrict__ dis, int N) {
  __shared__ int lcnt[BKT_NODES];
  __shared__ int lsum[BKT_NODES];
  __shared__ int lcur[BKT_NODES];
  __shared__ int stage[BKT_CAP];
  const int b = blockIdx.x;
  const int t = threadIdx.x;
  const int node0 = b << BKT_SHIFT;
  const int nn = min(BKT_NODES, N - node0);
  const int base = bbase[b];
  const int m = bbase[b + 1] - base;

  if (t < BKT_NODES) lcnt[t] = 0;
  __syncthreads();
  for (int i = t; i < m; i += 256) atomicAdd(&lcnt[grouped[base + i] >> 17], 1);
  __syncthreads();
  if (t < BKT_NODES) lsum[t] = lcnt[t];
  __syncthreads();
  for (int s = 1; s < BKT_NODES; s <<= 1) {
    int add = 0;
    if (t < BKT_NODES && t >= s) add = lsum[t - s];
    __syncthreads();
    if (t < BKT_NODES) lsum[t] += add;
    __syncthreads();
  }
  if (t < nn) {
    ends[node0 + t] = base + lsum[t];                      // global inclusive end
    dis[node0 + t] = 1.0f / sqrtf((float)(lcnt[t] + 1));   // +1 self loop
    lcur[t] = lsum[t] - lcnt[t];                           // local exclusive cursor
  }
  __syncthreads();
  if (m <= BKT_CAP) {
    for (int i = t; i < m; i += 256) {
      unsigned int v = grouped[base + i];
      int p = atomicAdd(&lcur[v >> 17], 1);
      stage[p] = (int)(v & 0x1FFFFu);
    }
    __syncthreads();
    for (int i = t; i < m; i += 256) csr_src[base + i] = stage[i];
  } else {  // statistically never; correctness fallback
    for (int i = t; i < m; i += 256) {
      unsigned int v = grouped[base + i];
      int p = atomicAdd(&lcur[v >> 17], 1);
      csr_src[base + p] = (int)(v & 0x1FFFFu);
    }
  }
}

// ------- MFMA GEMM: C[N,64] = fp16( (H[N,K] @ W[K,64]) * dis[row] ) -----
// 64 rows/block, 256 thr = 4 waves; wave w owns rows 16w..16w+15.
// Whole K staged: Hs[64][K] fp16, Ws[64][K] fp16 (= W^T), both XOR-swizzled.

template <int K, typename Tin>
__global__ __launch_bounds__(256) void gemm_mfma_kernel(
    const Tin* __restrict__ H, const float* __restrict__ W,
    const float* __restrict__ dis, __half* __restrict__ C, int N) {
  __shared__ __align__(16) __half Hs[64 * K];
  __shared__ __align__(16) __half Ws[64 * K];
  const int t = threadIdx.x;
  const int rowBase = blockIdx.x * 64;

  // ---- stage H (cast to fp16, swizzled) ----
  if constexpr (sizeof(Tin) == 4) {
    const int NF4 = 64 * K / 4;
#pragma unroll
    for (int i = 0; i < NF4 / 256; ++i) {
      int f = t + i * 256;
      int row = f / (K / 4);
      int c4 = f % (K / 4);
      int gr = rowBase + row;
      float4 v = make_float4(0.f, 0.f, 0.f, 0.f);
      if (gr < N) v = *reinterpret_cast<const float4*>(H + (long)gr * K + c4 * 4);
      union { uint2 u; __half2 h[2]; } pk;
      pk.h[0] = __floats2half2_rn(v.x, v.y);
      pk.h[1] = __floats2half2_rn(v.z, v.w);
      int byte = (row * K + c4 * 4) * 2;
      byte ^= (row & 7) << 4;
      *reinterpret_cast<uint2*>(reinterpret_cast<char*>(Hs) + byte) = pk.u;
    }
  } else {
    const int NC = 64 * K / 8;
#pragma unroll
    for (int i = 0; i < NC / 256; ++i) {
      int f = t + i * 256;
      int row = f / (K / 8);
      int c8 = f % (K / 8);
      int gr = rowBase + row;
      uint4 v = make_uint4(0u, 0u, 0u, 0u);
      if (gr < N) v = *reinterpret_cast<const uint4*>(H + (long)gr * K + c8 * 8);
      int byte = (row * K + c8 * 8) * 2;
      byte ^= (row & 7) << 4;
      *reinterpret_cast<uint4*>(reinterpret_cast<char*>(Hs) + byte) = v;
    }
  }

  // ---- stage W^T (transpose via half2 k-pairs, swizzled) ----
  {
    const int NU = (K / 2) * 16;  // (k-pair, col-quad) units
#pragma unroll
    for (int i = 0; i < NU / 256; ++i) {
      int u = t + i * 256;
      int kp = u >> 4;
      int cq = u & 15;
      const float4 w0 = *reinterpret_cast<const float4*>(W + (long)(2 * kp) * 64 + cq * 4);
      const float4 w1 = *reinterpret_cast<const float4*>(W + (long)(2 * kp + 1) * 64 + cq * 4);
#pragma unroll
      for (int j = 0; j < 4; ++j) {
        int c = cq * 4 + j;
        __half2 p = __floats2half2_rn((&w0.x)[j], (&w1.x)[j]);
        int byte = (c * K + 2 * kp) * 2;
        byte ^= (c & 7) << 4;
        *reinterpret_cast<__half2*>(reinterpret_cast<char*>(Ws) + byte) = p;
      }
    }
  }
  __syncthreads();

  // ---- MFMA: wave computes 16 rows x 64 cols ----
  const int w = t >> 6;
  const int l = t & 63;
  const int r = l & 15;
  const int g = l >> 4;
  const int rowL = 16 * w + r;
  f32x4 acc[4] = {{0.f, 0.f, 0.f, 0.f}, {0.f, 0.f, 0.f, 0.f},
                  {0.f, 0.f, 0.f, 0.f}, {0.f, 0.f, 0.f, 0.f}};
#pragma unroll
  for (int s = 0; s < K / 32; ++s) {
    int abyte = (rowL * K + s * 32 + g * 8) * 2;
    abyte ^= (rowL & 7) << 4;
    f16x8 afrag = *reinterpret_cast<const f16x8*>(reinterpret_cast<const char*>(Hs) + abyte);
#pragma unroll
    for (int n = 0; n < 4; ++n) {
      int col = n * 16 + r;
      int bbyte = (col * K + s * 32 + g * 8) * 2;
      bbyte ^= (col & 7) << 4;
      f16x8 bfrag = *reinterpret_cast<const f16x8*>(reinterpret_cast<const char*>(Ws) + bbyte);
      acc[n] = __builtin_amdgcn_mfma_f32_16x16x32_f16(afrag, bfrag, acc[n], 0, 0, 0);
    }
  }

  // ---- epilogue: scale by dis[row], round to fp16 ----
  const int outRow0 = rowBase + 16 * w + 4 * g;
#pragma unroll
  for (int j = 0; j < 4; ++j) {
    int row = outRow0 + j;
    if (row < N) {
      float dv = dis[row];
#pragma unroll
      for (int n = 0; n < 4; ++n) {
        C[(long)row * 64 + n * 16 + r] = __float2half(acc[n][j] * dv);
      }
    }
  }
}

// -------- aggregation: CSR, 16 lanes/node, 4 nodes/wave, deep ILP --------
// Lane (g,c) owns cols 4c..4c+3 of node d=wid*4+g. Chunks 0+1 (32 edges)
// fully staged: idx prefetched, 32 row-loads issued before ANY accumulate
// (pad lanes clamp to row d = L1-hot). Dynamic tail for degree>32 only.

__device__ __forceinline__ float4 h4_to_f4(uint2 u) {
  const __half2 lo = *reinterpret_cast<const __half2*>(&u.x);
  const __half2 hi = *reinterpret_cast<const __half2*>(&u.y);
  const float2 flo = __half22float2(lo);
  const float2 fhi = __half22float2(hi);
  return make_float4(flo.x, flo.y, fhi.x, fhi.y);
}

__global__ __launch_bounds__(256) void aggregate_kernel(
    const __half* __restrict__ Ts, const int* __restrict__ csr_src,
    const int* __restrict__ ends, const float* __restrict__ dis,
    const float* __restrict__ bias, __half* __restrict__ O, int N) {
  const int wid = (blockIdx.x * 256 + threadIdx.x) >> 6;
  const int l = threadIdx.x & 63;
  const int g = l >> 4;         // node within wave quad
  const int c = l & 15;         // uint2 column of the 128B row
  const int d0 = wid * 4 + g;
  const bool valid = d0 < N;
  const int d = valid ? d0 : (N - 1);   // safe row for pad lanes
  const int beg = valid ? ((d0 == 0) ? 0 : ends[d0 - 1]) : 0;
  const int m = valid ? (ends[d0] - beg) : 0;   // group-uniform per valid group
  const uint2* Tv = (const uint2*)Ts;

  // self loop (pre-scaled by dis[d])
  float4 a = h4_to_f4(Tv[(long)d * 16 + c]);

  // wave-uniform outer trip count so shfl stays convergent
  int mmax = m;
  mmax = max(mmax, __shfl_xor(mmax, 16, 64));
  mmax = max(mmax, __shfl_xor(mmax, 32, 64));

  const int gbase = l & 48;     // first lane of this group

  // ---- prefetch indices for chunks 0 and 1 ----
  int idx0 = (c < m) ? csr_src[beg + c] : 0;
  int idx1 = (16 + c < m) ? csr_src[beg + 16 + c] : 0;

  // ---- stage all 32 row loads before accumulating ----
  uint2 fr0[16], fr1[16];
  const bool has0 = (mmax > 0), has1 = (mmax > 16);
  if (has0) {
#pragma unroll
    for (int j = 0; j < 16; ++j) {
      int s = __shfl(idx0, gbase + j, 64);
      s = (j < m) ? s : d;              // pad -> own row (L1-hot)
      fr0[j] = Tv[(long)s * 16 + c];
    }
  }
  if (has1) {
#pragma unroll
    for (int j = 0; j < 16; ++j) {
      int s = __shfl(idx1, gbase + j, 64);
      s = (j + 16 < m) ? s : d;
      fr1[j] = Tv[(long)s * 16 + c];
    }
  }
  if (has0) {
#pragma unroll
    for (int j = 0; j < 16; ++j) {
      if (j < m) {
        float4 f = h4_to_f4(fr0[j]);
        a.x += f.x; a.y += f.y; a.z += f.z; a.w += f.w;
      }
    }
  }
  if (has1) {
#pragma unroll
    for (int j = 0; j < 16; ++j) {
      if (j + 16 < m) {
        float4 f = h4_to_f4(fr1[j]);
        a.x += f.x; a.y += f.y; a.z += f.z; a.w += f.w;
      }
    }
  }

  // ---- dynamic tail (degree > 32; Poisson(16) => rare) ----
  for (int base = 32; base < mmax; base += 16) {
    const int take = m - base;
    int idx = (base + c < m) ? csr_src[beg + base + c] : 0;
    uint2 fr[16];
#pragma unroll
    for (int j = 0; j < 16; ++j) {
      int s = __shfl(idx, gbase + j, 64);
      s = (j < take) ? s : d;
      fr[j] = Tv[(long)s * 16 + c];
    }
#pragma unroll
    for (int j = 0; j < 16; ++j) {
      if (j < take) {
        float4 f = h4_to_f4(fr[j]);
        a.x += f.x; a.y += f.y; a.z += f.z; a.w += f.w;
      }
    }
  }

  if (valid) {
    const float dd = dis[d0];
    const float4 b4 = ((const float4*)bias)[c];
    union { uint2 uu; __half2 h[2]; } pk;
    pk.h[0] = __floats2half2_rn(fmaxf(a.x * dd + b4.x, 0.f),
                                fmaxf(a.y * dd + b4.y, 0.f));
    pk.h[1] = __floats2half2_rn(fmaxf(a.z * dd + b4.z, 0.f),
                                fmaxf(a.w * dd + b4.w, 0.f));
    ((uint2*)O)[(long)d0 * 16 + c] = pk.uu;
  }
}

// -------- pooling (logits fused, 1024 thr = 16 waves for latency) --------

__global__ __launch_bounds__(1024) void pool_kernel(
    const __half* __restrict__ h3, const float* __restrict__ clo,
    const float* __restrict__ Wc, const float* __restrict__ bc,
    const int* __restrict__ batch, const float* __restrict__ Wa1,
    const float* __restrict__ ba1, const float* __restrict__ Wa2,
    const float* __restrict__ ba2, float* __restrict__ out, int N) {
  __shared__ int sLo, sHi;
  __shared__ float red[1024];
  __shared__ float Vs[16][64];
  __shared__ float sse[16];
  __shared__ float gv[64];
  __shared__ float am[16];
  const int g = blockIdx.x;
  const int t = threadIdx.x;
  if (t == 0) {
    int lo = 0, hi = N;
    while (lo < hi) { int mid = (lo + hi) >> 1; if (batch[mid] < g) lo = mid + 1; else hi = mid; }
    sLo = lo;
    lo = 0; hi = N;
    while (lo < hi) { int mid = (lo + hi) >> 1; if (batch[mid] < g + 1) lo = mid + 1; else hi = mid; }
    sHi = lo;
  }
  __syncthreads();
  const int lo = sLo, hi = sHi;

  // logits computed inline: lb(i) = dot(clo[i,0:8], Wc) + bc
  float wc[8];
#pragma unroll
  for (int k = 0; k < 8; ++k) wc[k] = Wc[k];
  const float bc0 = bc[0];

  float lm = -1e30f;
  for (int i = lo + t; i < hi; i += 1024) {
    const float4 c0 = *reinterpret_cast<const float4*>(clo + (long)i * 8);
    const float4 c1 = *reinterpret_cast<const float4*>(clo + (long)i * 8 + 4);
    float s = bc0 + c0.x * wc[0] + c0.y * wc[1] + c0.z * wc[2] + c0.w * wc[3]
                  + c1.x * wc[4] + c1.y * wc[5] + c1.z * wc[6] + c1.w * wc[7];
    lm = fmaxf(lm, s);
  }
  red[t] = lm;
  __syncthreads();
  for (int s = 512; s > 0; s >>= 1) {
    if (t < s) red[t] = fmaxf(red[t], red[t + s]);
    __syncthreads();
  }
  const float m = red[0];

  const int f = t & 63, sub = t >> 6;   // 16 sub-groups of one wave each
  float vacc = 0.f, seacc = 0.f;
  for (int i = lo + sub; i < hi; i += 16) {
    const float4 c0 = *reinterpret_cast<const float4*>(clo + (long)i * 8);
    const float4 c1 = *reinterpret_cast<const float4*>(clo + (long)i * 8 + 4);
    float s = bc0 + c0.x * wc[0] + c0.y * wc[1] + c0.z * wc[2] + c0.w * wc[3]
                  + c1.x * wc[4] + c1.y * wc[5] + c1.z * wc[6] + c1.w * wc[7];
    float e = expf(s - m);
    seacc += e;
    vacc += e * __half2float(h3[(long)i * 64 + f]);
  }
  Vs[sub][f] = vacc;
  if (f == 0) sse[sub] = seacc;
  __syncthreads();
  if (t < 64) {
    float se = 0.f, v = 0.f;
#pragma unroll
    for (int s2 = 0; s2 < 16; ++s2) { se += sse[s2]; v += Vs[s2][f]; }
    gv[f] = (se > 0.f) ? v / se : 0.f;
  }
  __syncthreads();
  if (t < 16) {
    float a = ba1[t];
#pragma unroll
    for (int k2 = 0; k2 < 64; ++k2) a += gv[k2] * Wa1[k2 * 16 + t];
    am[t] = a > 0.f ? a : 0.f;
  }
  __syncthreads();
  if (t == 0) {
    float o = ba2[0];
#pragma unroll
    for (int j = 0; j < 16; ++j) o += am[j] * Wa2[j];
    out[g] = o;
  }
}

// ---------------- launcher ----------------

extern "C" void kernel_launch(void* const* d_in, const int* in_sizes, int n_in,
                              void* d_out, int out_size, void* d_ws, size_t ws_size,
                              hipStream_t stream) {
  const float* x   = (const float*)d_in[0];
  const float* clo = (const float*)d_in[1];
  const float* W1  = (const float*)d_in[2];
  const float* b1  = (const float*)d_in[3];
  const float* W2  = (const float*)d_in[4];
  const float* b2  = (const float*)d_in[5];
  const float* W3  = (const float*)d_in[6];
  const float* b3  = (const float*)d_in[7];
  const float* Wc  = (const float*)d_in[8];
  const float* bc  = (const float*)d_in[9];
  const float* Wa1 = (const float*)d_in[10];
  const float* ba1 = (const float*)d_in[11];
  const float* Wa2 = (const float*)d_in[12];
  const float* ba2 = (const float*)d_in[13];
  const int* edge  = (const int*)d_in[14];
  const int* batch = (const int*)d_in[15];
  float* out = (float*)d_out;

  const int N = in_sizes[15];        // 100000
  const int E = in_sizes[14] / 2;    // 1600000
  const int G = out_size;            // 256
  const int NBKT = (N + BKT_NODES - 1) >> BKT_SHIFT;  // 782 (<=1024)
  const int NBLK = (E + EPB - 1) / EPB;               // 196 (<=256)

  const int* src = edge;
  const int* dst = edge + E;

  char* p = (char*)d_ws;
  auto alloc = [&](size_t bytes) -> char* {
    char* r = p;
    p += (bytes + 255) & ~(size_t)255;
    return r;
  };
  __half* tsbuf         = (__half*)alloc((size_t)N * 64 * sizeof(__half));
  __half* bufH          = (__half*)alloc((size_t)N * 64 * sizeof(__half));
  int*   csr_src        = (int*)  alloc((size_t)E * sizeof(int));
  unsigned int* grouped = (unsigned int*)alloc((size_t)E * sizeof(unsigned int));
  int*   hist           = (int*)  alloc((size_t)NBKT * NBLK * sizeof(int));
  int*   ebase          = (int*)  alloc((size_t)NBKT * NBLK * sizeof(int));
  int*   btot           = (int*)  alloc((size_t)NBKT * sizeof(int));
  int*   bbase          = (int*)  alloc((size_t)(NBKT + 1) * sizeof(int));
  int*   ends           = (int*)  alloc((size_t)N * sizeof(int));
  float* dis            = (float*)alloc((size_t)N * sizeof(float));
  (void)ws_size; (void)n_in;

  block_hist_kernel<<<NBLK, 1024, 0, stream>>>(dst, hist, E, NBKT, NBLK);
  row_scan_kernel<<<NBKT, 256, 0, stream>>>(hist, ebase, btot, NBLK);
  bucket_scan_kernel<<<1, 1024, 0, stream>>>(btot, bbase, E, NBKT);
  group_kernel<<<NBLK, 1024, 0, stream>>>(src, dst, bbase, ebase, hist, grouped, E, NBKT, NBLK);
  bucket_build_kernel<<<NBKT, 256, 0, stream>>>(grouped, bbase, csr_src, ends, dis, N);

  const int gGemm = (N + 63) / 64;
  const int gAgg  = (N + 15) / 16;   // 16 nodes per 256-thread block

  gemm_mfma_kernel<128, float><<<gGemm, 256, 0, stream>>>(x, W1, dis, tsbuf, N);
  aggregate_kernel<<<gAgg, 256, 0, stream>>>(tsbuf, csr_src, ends, dis, b1, bufH, N);
  gemm_mfma_kernel<64, __half><<<gGemm, 256, 0, stream>>>(bufH, W2, dis, tsbuf, N);
  aggregate_kernel<<<gAgg, 256, 0, stream>>>(tsbuf, csr_src, ends, dis, b2, bufH, N);
  gemm_mfma_kernel<64, __half><<<gGemm, 256, 0, stream>>>(bufH, W3, dis, tsbuf, N);
  aggregate_kernel<<<gAgg, 256, 0, stream>>>(tsbuf, csr_src, ends, dis, b3, bufH, N);

  pool_kernel<<<G, 1024, 0, stream>>>(bufH, clo, Wc, bc, batch, Wa1, ba1, Wa2, ba2, out, N);
}